// Round 3
// baseline (1177.497 us; speedup 1.0000x reference)
//
#include <hip/hip_runtime.h>

#define B_ 128
#define T_ 1024
#define D_ 128
#define H_ 128

typedef short bf16x8 __attribute__((ext_vector_type(8)));
typedef float f32x4 __attribute__((ext_vector_type(4)));

// round-to-nearest-even f32 -> bf16 (finite inputs only)
__device__ inline short f2bf(float f) {
    union { float f; unsigned u; } v; v.f = f;
    unsigned u = v.u;
    unsigned r = (u + 0x7fffu + ((u >> 16) & 1u)) >> 16;
    return (short)r;
}

// tanh(x) = 1 - 2/(1+e^{2x}); robust at +-inf of exp
__device__ inline float fast_tanh(float x) {
    float e = __expf(2.0f * x);
    return 1.0f - __fdividef(2.0f, 1.0f + e);
}

// Workgroup barrier draining ONLY LDS (lgkmcnt), not VMEM (CK-style).
// Scan's cross-wave dependency is LDS-only; its global loads (xu, no alias)
// and stores (st workspace, never read by scan) stay in flight.
__device__ inline void lds_barrier() {
    asm volatile("s_waitcnt lgkmcnt(0)\n\ts_barrier" ::: "memory");
}

// ---------------------------------------------------------------------------
// Kernel 1: xu = x@U + bu + bw  ->  d_out, packed in scan-lane order:
//   f32 offset ((t*8 + blk)*8 + n)*256 + l*4 + r  holds
//   xu[b = blk*16 + 4*(l>>4) + r][t][h = 16n + (l&15)]
// MFMA rows m = 4*tloc + bloc (4 t's x 4 b's per wave) so the C-layout lane
// (q,c) holds 4 consecutive b's of one (t,h): one dwordx4 store per n-tile,
// and the scan later does ONE dwordx4 load per lane per step.
// Grid 2048 x 256: blockIdx = tg*32 + bg; b_base = bg*4, t0 = tg*16.
// ---------------------------------------------------------------------------
__global__ __launch_bounds__(256) void xu_kernel(
    const float* __restrict__ x, const float* __restrict__ U,
    const float* __restrict__ bu, const float* __restrict__ bw,
    float* __restrict__ xu_out)
{
    __shared__ short uf[16384];  // packed B-frags of U (32 KB)
    const int tid  = threadIdx.x;
    const int lane = tid & 63;
    const int wave = tid >> 6;
    const int q = lane >> 4, c = lane & 15;

    const int bg = blockIdx.x & 31;   // b-group: b_base = bg*4
    const int tg = blockIdx.x >> 5;   // t-group: t0 = tg*16
    const int b_base = bg * 4;
    const int t0w = tg * 16 + wave * 4;  // this wave's 4 t's

    // Stage U: coalesced float4 reads, scatter bf16 into packed frag layout.
    // Frag slot for (k,h): nt=h>>4, cc=h&15, kk=k>>5, lq=(k>>3)&3, j=k&7.
#pragma unroll
    for (int i = 0; i < 16; ++i) {
        int f4 = i * 256 + tid;        // float4 index, 0..4095
        int k   = f4 >> 5;             // U row
        int hb  = (f4 & 31) * 4;       // U col base
        f32x4 v = *(const f32x4*)(U + k * H_ + hb);
        int kk = k >> 5, lq = (k >> 3) & 3, j = k & 7;
#pragma unroll
        for (int e = 0; e < 4; ++e) {
            int h = hb + e;
            uf[(((h >> 4) * 4 + kk) * 64 + lq * 16 + (h & 15)) * 8 + j] = f2bf(v[e]);
        }
    }

    // bias per n-tile: (bu + bw)[16nt + c]
    float bias[8];
#pragma unroll
    for (int nt = 0; nt < 8; ++nt) bias[nt] = bu[16 * nt + c] + bw[16 * nt + c];

    // A-frags: row m=c -> (b = b_base + (c&3), t = t0w + (c>>2)), k = 32kk+8q+j
    bf16x8 af[4];
    {
        const float* px = x + ((size_t)(b_base + (c & 3)) * T_ + (t0w + (c >> 2))) * D_ + 8 * q;
#pragma unroll
        for (int kk = 0; kk < 4; ++kk) {
            f32x4 a0 = *(const f32x4*)(px + 32 * kk);
            f32x4 a1 = *(const f32x4*)(px + 32 * kk + 4);
            bf16x8 f;
            f[0] = f2bf(a0[0]); f[1] = f2bf(a0[1]); f[2] = f2bf(a0[2]); f[3] = f2bf(a0[3]);
            f[4] = f2bf(a1[0]); f[5] = f2bf(a1[1]); f[6] = f2bf(a1[2]); f[7] = f2bf(a1[3]);
            af[kk] = f;
        }
    }
    __syncthreads();

    // C-layout row m=4q+r -> t = t0w + q, b = b_base + r
    const int blkb = bg >> 2;          // scan block id (b>>4)
    const int qs   = bg & 3;           // scan q' = (b_base & 15) >> 2
    const int tC   = t0w + q;
    float* pout = xu_out + (size_t)(tC * 8 + blkb) * 8 * 256 + (qs * 16 + c) * 4;

#pragma unroll
    for (int nt = 0; nt < 8; ++nt) {
        f32x4 acc = {bias[nt], bias[nt], bias[nt], bias[nt]};
#pragma unroll
        for (int kk = 0; kk < 4; ++kk)
            acc = __builtin_amdgcn_mfma_f32_16x16x32_bf16(
                af[kk], *(const bf16x8*)&uf[((nt * 4 + kk) * 64 + lane) * 8], acc, 0, 0, 0);
        *(f32x4*)(pout + nt * 256) = acc;  // 4 b's of one (t,h): scan-lane pack
    }
}

// ---------------------------------------------------------------------------
// Kernel 2: sequential scan, h-path ONLY. Grid = 8 blocks x 512 thr (8 waves).
// Wave n computes cols 16n..16n+15 of st_t = tanh(xu_t + st_{t-1}@W).
// st round-trips through LDS (the only cross-wave dependency -> lds_barrier).
// Each step also dumps st_{t-1} (the just-loaded A-frags, bf16 row-major
// [plane=t*8+blk][m=16][k=128]) to ws via 4 fire-and-forget dwordx4 stores;
// o_kernel consumes that afterwards.
// ---------------------------------------------------------------------------
__global__ __launch_bounds__(512) void scan_kernel(
    const float* __restrict__ xu,   // packed xu in d_out
    short* __restrict__ st_ws,      // bf16 st planes, 32 MB
    const float* __restrict__ h0,
    const float* __restrict__ W)
{
    __shared__ __align__(16) short st[2][16][136];  // +8 pad: 2-way alias, free

    const int tid  = threadIdx.x;
    const int lane = tid & 63;
    const int n    = tid >> 6;            // wave = n-tile 0..7
    const int q = lane >> 4, c = lane & 15;
    const int c0 = 16 * n;
    const int blk = blockIdx.x;
    const int b0  = blk * 16;

    // W B-frags held in registers for all 1024 steps
    bf16x8 wf[4];
#pragma unroll
    for (int kk = 0; kk < 4; ++kk) {
        bf16x8 f;
#pragma unroll
        for (int j = 0; j < 8; ++j)
            f[j] = f2bf(W[(32 * kk + 8 * q + j) * H_ + c0 + c]);
        wf[kk] = f;
    }

    // Stage h0 -> slot[1] (st_{-1}): 512 thr, 4 bf16 each, one b64 write
    {
        int m  = tid >> 5;        // 0..15
        int k0 = (tid & 31) * 4;  // 0..124
        f32x4 hv = *(const f32x4*)(h0 + (b0 + m) * H_ + k0);
        union { short s[4]; unsigned long long u; } pk;
        pk.s[0] = f2bf(hv[0]); pk.s[1] = f2bf(hv[1]);
        pk.s[2] = f2bf(hv[2]); pk.s[3] = f2bf(hv[3]);
        *(unsigned long long*)&st[1][m][k0] = pk.u;
    }

    // xu: one dwordx4 per lane per step; uniform stride 16384 f32 per t
    const float* pxu = xu + (blk * 8 + n) * 256 + lane * 4;
    // st_ws: plane p=t*8+blk -> short offset t*16384 + blk*2048; lane part m=c
    short* pst = st_ws + blk * 2048 + c * 128 + 8 * q;

    // 4-deep xu prefetch FIFO
    f32x4 xubuf[4];
#pragma unroll
    for (int u = 0; u < 4; ++u)
        xubuf[u] = *(const f32x4*)(pxu + u * 16384);

    lds_barrier();

    for (int tb = 0; tb < T_ / 4; ++tb) {
#pragma unroll
        for (int u = 0; u < 4; ++u) {
            const int t  = tb * 4 + u;
            const int pr = (u + 1) & 1;   // slot holding st_{t-1}
            const int pw = u & 1;         // slot for st_t

            f32x4 accA = xubuf[u];        // xu_t (+bu+bw already folded in)
            if (t + 4 < T_)
                xubuf[u] = *(const f32x4*)(pxu + (t + 4) * 16384);

            // A-frags: A[m=c][k=32kk+8q+j]
            bf16x8 af[4];
#pragma unroll
            for (int kk = 0; kk < 4; ++kk)
                af[kk] = *(const bf16x8*)&st[pr][c][32 * kk + 8 * q];

            // dump st_{t-1} = af to its plane (fire-and-forget, coalesced 16B)
            if (u > 0 || tb > 0) {
                short* pp = pst + (t - 1) * 16384;
#pragma unroll
                for (int kk = 0; kk < 4; ++kk)
                    *(bf16x8*)(pp + 32 * kk) = af[kk];
            }

            f32x4 accB = {0.f, 0.f, 0.f, 0.f};
            accA = __builtin_amdgcn_mfma_f32_16x16x32_bf16(af[0], wf[0], accA, 0, 0, 0);
            accB = __builtin_amdgcn_mfma_f32_16x16x32_bf16(af[1], wf[1], accB, 0, 0, 0);
            accA = __builtin_amdgcn_mfma_f32_16x16x32_bf16(af[2], wf[2], accA, 0, 0, 0);
            accB = __builtin_amdgcn_mfma_f32_16x16x32_bf16(af[3], wf[3], accB, 0, 0, 0);
#pragma unroll
            for (int r = 0; r < 4; ++r) {
                float s = fast_tanh(accA[r] + accB[r]);
                st[pw][4 * q + r][c0 + c] = f2bf(s);
            }
            lds_barrier();
        }
    }

    // epilogue: dump st_{T-1} (lives in slot[(T-1)&1] = slot[1])
    {
        short* pp = pst + (T_ - 1) * 16384;
#pragma unroll
        for (int kk = 0; kk < 4; ++kk) {
            bf16x8 a = *(const bf16x8*)&st[1][c][32 * kk + 8 * q];
            *(bf16x8*)(pp + 32 * kk) = a;
        }
    }
}

// ---------------------------------------------------------------------------
// Kernel 3: o = tanh(st@V + bv) -> out[b][t][h] f32. Full-device GEMM+tanh.
// Grid 2048 x 256: each wave handles one plane (t,blk) = 16x128 st tile,
// read directly from ws as bf16 A-frags (coalesced dwordx4).
// ---------------------------------------------------------------------------
__global__ __launch_bounds__(256) void o_kernel(
    const short* __restrict__ st_ws, const float* __restrict__ V,
    const float* __restrict__ bv, float* __restrict__ out)
{
    __shared__ short vf[16384];  // packed B-frags of V
    const int tid  = threadIdx.x;
    const int lane = tid & 63;
    const int wave = tid >> 6;
    const int q = lane >> 4, c = lane & 15;

    // Stage V (same scheme as U)
#pragma unroll
    for (int i = 0; i < 16; ++i) {
        int f4 = i * 256 + tid;
        int k  = f4 >> 5;
        int hb = (f4 & 31) * 4;
        f32x4 v = *(const f32x4*)(V + k * H_ + hb);
        int kk = k >> 5, lq = (k >> 3) & 3, j = k & 7;
#pragma unroll
        for (int e = 0; e < 4; ++e) {
            int h = hb + e;
            vf[(((h >> 4) * 4 + kk) * 64 + lq * 16 + (h & 15)) * 8 + j] = f2bf(v[e]);
        }
    }

    float bias[8];
#pragma unroll
    for (int nt = 0; nt < 8; ++nt) bias[nt] = bv[16 * nt + c];

    const int p   = blockIdx.x * 4 + wave;  // plane 0..8191
    const int t   = p >> 3;
    const int blk = p & 7;

    // A-frags straight from global bf16: A[m=c][k=32kk+8q+j]
    const short* ps = st_ws + (size_t)p * 2048 + c * 128 + 8 * q;
    bf16x8 af[4];
#pragma unroll
    for (int kk = 0; kk < 4; ++kk)
        af[kk] = *(const bf16x8*)(ps + 32 * kk);

    __syncthreads();

    float* po = out + ((size_t)(blk * 16 + 4 * q) * T_ + t) * H_ + c;
#pragma unroll
    for (int nt = 0; nt < 8; ++nt) {
        f32x4 acc = {bias[nt], bias[nt], bias[nt], bias[nt]};
#pragma unroll
        for (int kk = 0; kk < 4; ++kk)
            acc = __builtin_amdgcn_mfma_f32_16x16x32_bf16(
                af[kk], *(const bf16x8*)&vf[((nt * 4 + kk) * 64 + lane) * 8], acc, 0, 0, 0);
#pragma unroll
        for (int r = 0; r < 4; ++r)
            po[(size_t)r * T_ * H_ + 16 * nt] = fast_tanh(acc[r]);
    }
}

extern "C" void kernel_launch(void* const* d_in, const int* in_sizes, int n_in,
                              void* d_out, int out_size, void* d_ws, size_t ws_size,
                              hipStream_t stream) {
    const float* x  = (const float*)d_in[0];
    const float* h0 = (const float*)d_in[1];
    const float* U  = (const float*)d_in[2];
    const float* W  = (const float*)d_in[3];
    const float* V  = (const float*)d_in[4];
    const float* bu = (const float*)d_in[5];
    const float* bw = (const float*)d_in[6];
    const float* bv = (const float*)d_in[7];
    float* out = (float*)d_out;
    short* st_ws = (short*)d_ws;   // 8192 planes x 4 KB = 32 MB

    // 1) xu = x@U + bu + bw, packed into d_out (consumed by scan)
    xu_kernel<<<2048, 256, 0, stream>>>(x, U, bu, bw, out);
    // 2) sequential recurrence; dumps st planes (bf16) to d_ws
    scan_kernel<<<8, 512, 0, stream>>>(out, st_ws, h0, W);
    // 3) o = tanh(st@V + bv), overwrites d_out with final [B][T][H]
    o_kernel<<<2048, 256, 0, stream>>>(st_ws, V, bv, out);
}

// Round 4
// 1029.450 us; speedup vs baseline: 1.1438x; 1.1438x over previous
//
#include <hip/hip_runtime.h>

#define B_ 128
#define T_ 1024
#define D_ 128
#define H_ 128

typedef short bf16x8 __attribute__((ext_vector_type(8)));
typedef float f32x4 __attribute__((ext_vector_type(4)));

// round-to-nearest-even f32 -> bf16 (finite inputs only)
__device__ inline short f2bf(float f) {
    union { float f; unsigned u; } v; v.f = f;
    unsigned u = v.u;
    unsigned r = (u + 0x7fffu + ((u >> 16) & 1u)) >> 16;
    return (short)r;
}

// tanh(x) = 1 - 2/(1+e^{2x}); robust at +-inf of exp
__device__ inline float fast_tanh(float x) {
    float e = __expf(2.0f * x);
    return 1.0f - __fdividef(2.0f, 1.0f + e);
}

// Barrier draining ONLY LDS (lgkmcnt), not VMEM. The scan's cross-wave
// dependency is LDS-only (st slots); global_load_lds DMAs and st-dump
// stores stay in flight across it.
__device__ inline void lds_barrier() {
    asm volatile("s_waitcnt lgkmcnt(0)\n\ts_barrier" ::: "memory");
}
__device__ inline void full_barrier() {
    asm volatile("s_waitcnt vmcnt(0) lgkmcnt(0)\n\ts_barrier" ::: "memory");
}
// Drain VMEM down to 12 outstanding: by the time plane t is consumed its
// DMA is >=25 ops deep in the per-wave queue (5 ops/step x 5-step prefetch
// distance), so this guarantees it landed with margin ~13, and only waits
// on ops >=2.5 steps old (already retired) -> ~free.
__device__ inline void wait_vm12() {
    asm volatile("s_waitcnt vmcnt(12)" ::: "memory");
}

typedef __attribute__((address_space(1))) const void gas_void;
typedef __attribute__((address_space(3))) void las_void;
// async global->LDS DMA, 16 B/lane; LDS dst = wave-uniform base + lane*16
__device__ inline void async_ld16(const float* g, void* l) {
    __builtin_amdgcn_global_load_lds((gas_void*)g, (las_void*)l, 16, 0, 0);
}

// ---------------------------------------------------------------------------
// Kernel 1: xu = x@U + bu + bw -> d_out, packed in scan-lane order:
//   f32 offset ((t*8 + blk)*8 + n)*256 + l*4 + r  holds
//   xu[b = blk*16 + 4*(l>>4) + r][t][h = 16n + (l&15)]
// 512 blocks x 256 thr; U staged once per block, 4 row-tiles per block.
// ---------------------------------------------------------------------------
__global__ __launch_bounds__(256) void xu_kernel(
    const float* __restrict__ x, const float* __restrict__ U,
    const float* __restrict__ bu, const float* __restrict__ bw,
    float* __restrict__ xu_out)
{
    __shared__ short uf[16384];  // packed B-frags of U (32 KB)
    const int tid  = threadIdx.x;
    const int lane = tid & 63;
    const int wave = tid >> 6;
    const int q = lane >> 4, c = lane & 15;

    // Stage U: coalesced float4 reads, scatter bf16 into packed frag layout.
#pragma unroll
    for (int i = 0; i < 16; ++i) {
        int f4 = i * 256 + tid;        // float4 index, 0..4095
        int k   = f4 >> 5;             // U row
        int hb  = (f4 & 31) * 4;       // U col base
        f32x4 v = *(const f32x4*)(U + k * H_ + hb);
        int kk = k >> 5, lq = (k >> 3) & 3, j = k & 7;
#pragma unroll
        for (int e = 0; e < 4; ++e) {
            int h = hb + e;
            uf[(((h >> 4) * 4 + kk) * 64 + lq * 16 + (h & 15)) * 8 + j] = f2bf(v[e]);
        }
    }

    float bias[8];
#pragma unroll
    for (int nt = 0; nt < 8; ++nt) bias[nt] = bu[16 * nt + c] + bw[16 * nt + c];

    __syncthreads();

    for (int it = 0; it < 4; ++it) {
        const int vb = blockIdx.x * 4 + it;   // virtual block 0..2047
        const int bg = vb & 31;               // b-group: b_base = bg*4
        const int tg = vb >> 5;               // t-group: t0 = tg*16
        const int b_base = bg * 4;
        const int t0w = tg * 16 + wave * 4;

        // A-frags: row m=c -> (b = b_base + (c&3), t = t0w + (c>>2))
        bf16x8 af[4];
        {
            const float* px = x + ((size_t)(b_base + (c & 3)) * T_ + (t0w + (c >> 2))) * D_ + 8 * q;
#pragma unroll
            for (int kk = 0; kk < 4; ++kk) {
                f32x4 a0 = *(const f32x4*)(px + 32 * kk);
                f32x4 a1 = *(const f32x4*)(px + 32 * kk + 4);
                bf16x8 f;
                f[0] = f2bf(a0[0]); f[1] = f2bf(a0[1]); f[2] = f2bf(a0[2]); f[3] = f2bf(a0[3]);
                f[4] = f2bf(a1[0]); f[5] = f2bf(a1[1]); f[6] = f2bf(a1[2]); f[7] = f2bf(a1[3]);
                af[kk] = f;
            }
        }

        // C-layout row m=4q+r -> t = t0w + q, b = b_base + r
        const int blkb = bg >> 2;
        const int qs   = bg & 3;
        const int tC   = t0w + q;
        float* pout = xu_out + (size_t)(tC * 8 + blkb) * 8 * 256 + (qs * 16 + c) * 4;

#pragma unroll
        for (int nt = 0; nt < 8; ++nt) {
            f32x4 acc = {bias[nt], bias[nt], bias[nt], bias[nt]};
#pragma unroll
            for (int kk = 0; kk < 4; ++kk)
                acc = __builtin_amdgcn_mfma_f32_16x16x32_bf16(
                    af[kk], *(const bf16x8*)&uf[((nt * 4 + kk) * 64 + lane) * 8], acc, 0, 0, 0);
            *(f32x4*)(pout + nt * 256) = acc;
        }
    }
}

// ---------------------------------------------------------------------------
// Kernel 2: sequential scan, h-path only. Grid = 8 blocks x 512 thr (8 waves).
// Wave n: cols 16n..16n+15 of st_t = tanh(xu_t + st_{t-1}@W).
// xu staged via global_load_lds DMA into a 6-slot LDS ring (per-wave private
// slices, prefetch distance 5); st round-trips through LDS (lds_barrier).
// st_{t-1} dumped to ws once (exec-masked: lanes 8n..8n+7 of wave n),
// 4 KB/step/CU total.
// ---------------------------------------------------------------------------
__global__ __launch_bounds__(512) void scan_kernel(
    const float* __restrict__ xu,   // packed xu in d_out
    short* __restrict__ st_ws,      // bf16 st planes, 32 MB
    const float* __restrict__ h0,
    const float* __restrict__ W)
{
    __shared__ __align__(16) short st[2][16][136];       // 8704 B
    __shared__ __align__(16) float xubuf[6][8][256];     // 49152 B ring

    const int tid  = threadIdx.x;
    const int lane = tid & 63;
    const int n    = tid >> 6;            // wave = n-tile 0..7
    const int q = lane >> 4, c = lane & 15;
    const int c0 = 16 * n;
    const int blk = blockIdx.x;
    const int b0  = blk * 16;

    // W B-frags held in registers for all 1024 steps
    bf16x8 wf[4];
#pragma unroll
    for (int kk = 0; kk < 4; ++kk) {
        bf16x8 f;
#pragma unroll
        for (int j = 0; j < 8; ++j)
            f[j] = f2bf(W[(32 * kk + 8 * q + j) * H_ + c0 + c]);
        wf[kk] = f;
    }

    // Stage h0 -> slot[1] (st_{-1})
    {
        int m  = tid >> 5;        // 0..15
        int k0 = (tid & 31) * 4;  // 0..124
        f32x4 hv = *(const f32x4*)(h0 + (b0 + m) * H_ + k0);
        union { short s[4]; unsigned long long u; } pk;
        pk.s[0] = f2bf(hv[0]); pk.s[1] = f2bf(hv[1]);
        pk.s[2] = f2bf(hv[2]); pk.s[3] = f2bf(hv[3]);
        *(unsigned long long*)&st[1][m][k0] = pk.u;
    }

    // xu addressing: plane t at xu + t*16384 + blk*2048 + n*256 (+lane*4)
    const float* gbase = xu + blk * 2048 + n * 256 + lane * 4;
    char* lbase = (char*)&xubuf[0][0][0] + n * 1024;  // wave slice base

    // initial fill: planes 0..4 -> slots 0..4
#pragma unroll
    for (int u = 0; u < 5; ++u)
        async_ld16(gbase + u * 16384, lbase + u * 8192);

    full_barrier();

    const bool stlane = ((lane >> 3) == n);            // 8 lanes/wave store
    short* pstb = st_ws + blk * 2048 + c * 128 + 8 * q; // + t*16384 + 32*kk

    const float* gpre = gbase + 5 * 16384;  // next plane to DMA
    int roff = 0;            // ring byte offset of plane t
    int woff = 5 * 8192;     // ring byte offset for plane t+5

    for (int tb = 0; tb < T_ / 2; ++tb) {
#pragma unroll
        for (int u = 0; u < 2; ++u) {
            const int t  = tb * 2 + u;
            const int pr = (u + 1) & 1;   // slot holding st_{t-1}
            const int pw = u & 1;         // slot for st_t

            if (t + 5 < T_) {             // DMA plane t+5 into ring
                async_ld16(gpre, lbase + woff);
                gpre += 16384;
                woff += 8192; if (woff == 49152) woff = 0;
            }

            wait_vm12();                  // guarantees plane t landed
            f32x4 accA = *(const f32x4*)(lbase + roff + lane * 16);
            roff += 8192; if (roff == 49152) roff = 0;

            // A-frags: A[m=c][k=32kk+8q+j]
            bf16x8 af[4];
#pragma unroll
            for (int kk = 0; kk < 4; ++kk)
                af[kk] = *(const bf16x8*)&st[pr][c][32 * kk + 8 * q];

            // dump st_{t-1}: wave n's lanes 8n..8n+7 cover all (q,c) once
            if (t > 0 && stlane) {
                short* pp = pstb + (t - 1) * 16384;
                *(bf16x8*)(pp)      = af[0];
                *(bf16x8*)(pp + 32) = af[1];
                *(bf16x8*)(pp + 64) = af[2];
                *(bf16x8*)(pp + 96) = af[3];
            }

            f32x4 accB = {0.f, 0.f, 0.f, 0.f};
            accA = __builtin_amdgcn_mfma_f32_16x16x32_bf16(af[0], wf[0], accA, 0, 0, 0);
            accB = __builtin_amdgcn_mfma_f32_16x16x32_bf16(af[1], wf[1], accB, 0, 0, 0);
            accA = __builtin_amdgcn_mfma_f32_16x16x32_bf16(af[2], wf[2], accA, 0, 0, 0);
            accB = __builtin_amdgcn_mfma_f32_16x16x32_bf16(af[3], wf[3], accB, 0, 0, 0);
#pragma unroll
            for (int r = 0; r < 4; ++r) {
                float s = fast_tanh(accA[r] + accB[r]);
                st[pw][4 * q + r][c0 + c] = f2bf(s);
            }
            lds_barrier();
        }
    }

    // epilogue: dump st_{T-1} (slot[(T-1)&1] = slot[1])
    if (stlane) {
        short* pp = pstb + (T_ - 1) * 16384;
#pragma unroll
        for (int kk = 0; kk < 4; ++kk)
            *(bf16x8*)(pp + 32 * kk) = *(const bf16x8*)&st[1][c][32 * kk + 8 * q];
    }
}

// ---------------------------------------------------------------------------
// Kernel 3: o = tanh(st@V + bv) -> out[b][t][h] f32.
// 512 blocks x 256 thr; V staged once per block, 16 planes per block.
// ---------------------------------------------------------------------------
__global__ __launch_bounds__(256) void o_kernel(
    const short* __restrict__ st_ws, const float* __restrict__ V,
    const float* __restrict__ bv, float* __restrict__ out)
{
    __shared__ short vf[16384];
    const int tid  = threadIdx.x;
    const int lane = tid & 63;
    const int wave = tid >> 6;
    const int q = lane >> 4, c = lane & 15;

#pragma unroll
    for (int i = 0; i < 16; ++i) {
        int f4 = i * 256 + tid;
        int k  = f4 >> 5;
        int hb = (f4 & 31) * 4;
        f32x4 v = *(const f32x4*)(V + k * H_ + hb);
        int kk = k >> 5, lq = (k >> 3) & 3, j = k & 7;
#pragma unroll
        for (int e = 0; e < 4; ++e) {
            int h = hb + e;
            vf[(((h >> 4) * 4 + kk) * 64 + lq * 16 + (h & 15)) * 8 + j] = f2bf(v[e]);
        }
    }

    float bias[8];
#pragma unroll
    for (int nt = 0; nt < 8; ++nt) bias[nt] = bv[16 * nt + c];

    __syncthreads();

    for (int it = 0; it < 4; ++it) {
        const int p   = (blockIdx.x * 4 + it) * 4 + wave;  // plane 0..8191
        const int t   = p >> 3;
        const int blk = p & 7;

        const short* ps = st_ws + (size_t)p * 2048 + c * 128 + 8 * q;
        bf16x8 af[4];
#pragma unroll
        for (int kk = 0; kk < 4; ++kk)
            af[kk] = *(const bf16x8*)(ps + 32 * kk);

        float* po = out + ((size_t)(blk * 16 + 4 * q) * T_ + t) * H_ + c;
#pragma unroll
        for (int nt = 0; nt < 8; ++nt) {
            f32x4 acc = {bias[nt], bias[nt], bias[nt], bias[nt]};
#pragma unroll
            for (int kk = 0; kk < 4; ++kk)
                acc = __builtin_amdgcn_mfma_f32_16x16x32_bf16(
                    af[kk], *(const bf16x8*)&vf[((nt * 4 + kk) * 64 + lane) * 8], acc, 0, 0, 0);
#pragma unroll
            for (int r = 0; r < 4; ++r)
                po[(size_t)r * T_ * H_ + 16 * nt] = fast_tanh(acc[r]);
        }
    }
}

extern "C" void kernel_launch(void* const* d_in, const int* in_sizes, int n_in,
                              void* d_out, int out_size, void* d_ws, size_t ws_size,
                              hipStream_t stream) {
    const float* x  = (const float*)d_in[0];
    const float* h0 = (const float*)d_in[1];
    const float* U  = (const float*)d_in[2];
    const float* W  = (const float*)d_in[3];
    const float* V  = (const float*)d_in[4];
    const float* bu = (const float*)d_in[5];
    const float* bw = (const float*)d_in[6];
    const float* bv = (const float*)d_in[7];
    float* out = (float*)d_out;
    short* st_ws = (short*)d_ws;   // 8192 planes x 4 KB = 32 MB

    // 1) xu = x@U + bu + bw, packed into d_out (consumed by scan)
    xu_kernel<<<512, 256, 0, stream>>>(x, U, bu, bw, out);
    // 2) sequential recurrence; dumps st planes (bf16) to d_ws
    scan_kernel<<<8, 512, 0, stream>>>(out, st_ws, h0, W);
    // 3) o = tanh(st@V + bv), overwrites d_out with final [B][T][H]
    o_kernel<<<512, 256, 0, stream>>>(st_ws, V, bv, out);
}